// Round 1
// baseline (312.147 us; speedup 1.0000x reference)
//
#include <hip/hip_runtime.h>

#define Bb 8
#define Cc 8
#define Ff 257
#define Tt 1500
#define P2 750            // Tt/2 (float2 elements)
#define BF (Bb*Ff)        // 2056

__device__ __forceinline__ constexpr int utIdx(int c, int d) { return c*(17-c)/2 + (d-c); }      // c<=d, 36 vals
__device__ __forceinline__ constexpr int odIdx(int c, int d) { return 7*c - c*(c-1)/2 + (d-c-1); } // c<d, 28 vals

constexpr float EPSv   = 1e-8f;
constexpr float PSDEPS = 1e-5f;
constexpr float IMADD  = 1e-5f + 1e-8f;   // +1j*PSD_EPS (inside _estimate_psd) +1j*eps (outside)

// ---------------- mask max, stage 1: partial max over F-chunks ----------------
__global__ void mask_pmax(const float* __restrict__ sm, const float* __restrict__ nm,
                          float* __restrict__ pmax_s, float* __restrict__ pmax_n) {
    int t  = blockIdx.x * 256 + threadIdx.x;
    int ch = blockIdx.y;
    int b  = blockIdx.z;
    if (t >= Tt) return;
    int f0 = ch * 33, f1 = min(Ff, f0 + 33);
    float ms = 0.f, mn = 0.f;
    for (int f = f0; f < f1; ++f) {
        ms = fmaxf(ms, fabsf(sm[(b*Ff + f)*Tt + t]));
        mn = fmaxf(mn, fabsf(nm[(b*Ff + f)*Tt + t]));
    }
    pmax_s[(b*8 + ch)*Tt + t] = ms;
    pmax_n[(b*8 + ch)*Tt + t] = mn;
}

// ---------------- mask max, stage 2: combine chunks -> 1/(max+eps) ----------------
__global__ void mask_inv(const float* __restrict__ pmax_s, const float* __restrict__ pmax_n,
                         float* __restrict__ inv_s, float* __restrict__ inv_n) {
    int t = blockIdx.x * 256 + threadIdx.x;
    int b = blockIdx.y;
    if (t >= Tt) return;
    float ms = 0.f, mn = 0.f;
    #pragma unroll
    for (int ch = 0; ch < 8; ++ch) {
        ms = fmaxf(ms, pmax_s[(b*8 + ch)*Tt + t]);
        mn = fmaxf(mn, pmax_n[(b*8 + ch)*Tt + t]);
    }
    inv_s[b*Tt + t] = 1.0f / (ms + EPSv);
    inv_n[b*Tt + t] = 1.0f / (mn + EPSv);
}

// ---------------- main fused kernel: one block (1 wave) per (b,f) ----------------
__global__ __launch_bounds__(64, 2) void mvdr_main(
    const float* __restrict__ smask, const float* __restrict__ nmask,
    const float* __restrict__ cmr,   const float* __restrict__ cmi,
    const float* __restrict__ inv_s, const float* __restrict__ inv_n,
    float* __restrict__ out)
{
    const int blk = blockIdx.x;
    const int b = blk / Ff, f = blk % Ff;
    const int tid = threadIdx.x;

    const float2* sm2 = (const float2*)smask + (b*Ff + f)*P2;
    const float2* nm2 = (const float2*)nmask + (b*Ff + f)*P2;
    const float2* is2 = (const float2*)inv_s + b*P2;
    const float2* in2 = (const float2*)inv_n + b*P2;
    const int cstride = Ff * P2;                       // float2 per (b,c) plane
    const float2* xr2 = (const float2*)cmr + (b*Cc)*cstride + f*P2;
    const float2* xi2 = (const float2*)cmi + (b*Cc)*cstride + f*P2;

    // ---- Phase A: weighted covariance accumulation (registers) ----
    float accS[64], accN[64];
    #pragma unroll
    for (int v = 0; v < 64; ++v) { accS[v] = 0.f; accN[v] = 0.f; }
    float sum_ms = 0.f, sum_mn = 0.f;

    for (int p = tid; p < P2; p += 64) {
        float2 s2  = sm2[p], n2v = nm2[p];
        float2 i2s = is2[p], i2n = in2[p];
        float2 xr[8], xi[8];
        #pragma unroll
        for (int c = 0; c < 8; ++c) { xr[c] = xr2[p + c*cstride]; xi[c] = xi2[p + c*cstride]; }
        float msx = s2.x * i2s.x, msy = s2.y * i2s.y;
        float mnx = n2v.x * i2n.x, mny = n2v.y * i2n.y;
        sum_ms += msx + msy; sum_mn += mnx + mny;
        #pragma unroll
        for (int c = 0; c < 8; ++c) {
            float sax = msx*xr[c].x, say = msy*xr[c].y, sbx = msx*xi[c].x, sby = msy*xi[c].y;
            float nax = mnx*xr[c].x, nay = mny*xr[c].y, nbx = mnx*xi[c].x, nby = mny*xi[c].y;
            #pragma unroll
            for (int d = c; d < 8; ++d) {
                const int k = utIdx(c, d);
                accS[k] += sax*xr[d].x + sbx*xi[d].x + say*xr[d].y + sby*xi[d].y;
                accN[k] += nax*xr[d].x + nbx*xi[d].x + nay*xr[d].y + nby*xi[d].y;
                if (d > c) {
                    const int j = 36 + odIdx(c, d);
                    accS[j] += sbx*xr[d].x - sax*xi[d].x + sby*xr[d].y - say*xi[d].y;
                    accN[j] += nbx*xr[d].x - nax*xi[d].x + nby*xr[d].y - nay*xi[d].y;
                }
            }
        }
    }

    // mask sums: wave butterfly (only 2 values)
    #pragma unroll
    for (int o = 32; o; o >>= 1) {
        sum_ms += __shfl_xor(sum_ms, o, 64);
        sum_mn += __shfl_xor(sum_mn, o, 64);
    }
    const float den_s = fmaxf(sum_ms, PSDEPS);
    const float den_n = fmaxf(sum_mn, PSDEPS);

    // ---- cross-lane reduction: LDS transpose, 2 rounds of 64 values ----
    __shared__ float red[64*68];
    #pragma unroll
    for (int v = 0; v < 64; ++v) red[v*68 + tid] = accS[v];
    __syncthreads();
    float Sval = 0.f;
    {
        const float4* row = (const float4*)(red + tid*68);
        #pragma unroll
        for (int q = 0; q < 16; ++q) { float4 r4 = row[q]; Sval += r4.x + r4.y + r4.z + r4.w; }
    }
    __syncthreads();
    #pragma unroll
    for (int v = 0; v < 64; ++v) red[v*68 + tid] = accN[v];
    __syncthreads();
    float Nval = 0.f;
    {
        const float4* row = (const float4*)(red + tid*68);
        #pragma unroll
        for (int q = 0; q < 16; ++q) { float4 r4 = row[q]; Nval += r4.x + r4.y + r4.z + r4.w; }
    }

    // ---- build S matrix and augmented [N | I] in LDS ----
    __shared__ float SreM[64], SimM[64];
    __shared__ float Are[128], Aim[128];
    __shared__ float dre[8], dim_[8], wre[8], wim[8];

    {
        int cc_, dd_;
        if (tid < 36) { int k = tid, c = 0; while (k >= 8 - c) { k -= 8 - c; ++c; } cc_ = c; dd_ = c + k; }
        else          { int k = tid - 36, c = 0; while (k >= 7 - c) { k -= 7 - c; ++c; } cc_ = c; dd_ = c + k + 1; }
        float sv = Sval / den_s, nv = Nval / den_n;
        if (tid < 36) {
            SreM[cc_*8 + dd_] = sv; SreM[dd_*8 + cc_] = sv;
            float nvd = nv + (cc_ == dd_ ? EPSv : 0.f);   // + eye*eps on noise diag
            Are[cc_*16 + dd_] = nvd; Are[dd_*16 + cc_] = nvd;
            if (cc_ == dd_) { SimM[cc_*8 + cc_] = IMADD; Aim[cc_*16 + cc_] = IMADD; }
        } else {
            SimM[cc_*8 + dd_] = IMADD + sv; SimM[dd_*8 + cc_] = IMADD - sv;
            Aim[cc_*16 + dd_] = IMADD + nv; Aim[dd_*16 + cc_] = IMADD - nv;
        }
        int r = tid >> 3, j = tid & 7;                    // identity right half
        Are[r*16 + 8 + j] = (r == j) ? 1.f : 0.f;
        Aim[r*16 + 8 + j] = 0.f;
    }
    __syncthreads();

    // ---- Gauss-Jordan inverse of N (unpivoted; N ~ HPD + tiny perturbation) ----
    // lane owns cells (r, cA) and (r, cA+8) of the 8x16 augmented matrix
    {
        const int r = tid >> 3, cA = tid & 7;
        for (int k = 0; k < 8; ++k) {
            float pr = Are[k*16 + k], pi = Aim[k*16 + k];
            float idn = 1.0f / (pr*pr + pi*pi);
            float ipr = pr*idn, ipi = -pi*idn;
            if (r == k) {
                float ar0 = Are[k*16 + cA],     ai0 = Aim[k*16 + cA];
                Are[k*16 + cA]     = ar0*ipr - ai0*ipi; Aim[k*16 + cA]     = ar0*ipi + ai0*ipr;
                float ar1 = Are[k*16 + cA + 8], ai1 = Aim[k*16 + cA + 8];
                Are[k*16 + cA + 8] = ar1*ipr - ai1*ipi; Aim[k*16 + cA + 8] = ar1*ipi + ai1*ipr;
            }
            __syncthreads();
            float fr = Are[r*16 + k], fi = Aim[r*16 + k];
            float p0r = Are[k*16 + cA],     p0i = Aim[k*16 + cA];
            float p1r = Are[k*16 + cA + 8], p1i = Aim[k*16 + cA + 8];
            float o0r = 0.f, o0i = 0.f, o1r = 0.f, o1i = 0.f;
            if (r != k) {
                o0r = Are[r*16 + cA]     - (fr*p0r - fi*p0i);
                o0i = Aim[r*16 + cA]     - (fr*p0i + fi*p0r);
                o1r = Are[r*16 + cA + 8] - (fr*p1r - fi*p1i);
                o1i = Aim[r*16 + cA + 8] - (fr*p1i + fi*p1r);
            }
            __syncthreads();
            if (r != k) {
                Are[r*16 + cA]     = o0r; Aim[r*16 + cA]     = o0i;
                Are[r*16 + cA + 8] = o1r; Aim[r*16 + cA + 8] = o1i;
            }
            __syncthreads();
        }
    }

    // ---- u = inv@S e0, partial traces ----
    if (tid < 8) {
        int c = tid;
        float ur = 0.f, ui = 0.f, tr_r = 0.f, tr_i = 0.f;
        #pragma unroll
        for (int j = 0; j < 8; ++j) {
            float vr = Are[c*16 + 8 + j], vi = Aim[c*16 + 8 + j] + EPSv;  // inv + 1j*eps
            float s0r = SreM[j*8 + 0], s0i = SimM[j*8 + 0];
            ur += vr*s0r - vi*s0i; ui += vr*s0i + vi*s0r;
            float scr = SreM[j*8 + c], sci = SimM[j*8 + c];
            tr_r += vr*scr - vi*sci; tr_i += vr*sci + vi*scr;
        }
        dre[c] = tr_r; dim_[c] = tr_i;
        wre[c] = ur;   wim[c]  = ui;
    }
    __syncthreads();
    if (tid < 8) {
        float tr_r = EPSv, tr_i = 0.f;
        #pragma unroll
        for (int j = 0; j < 8; ++j) { tr_r += dre[j]; tr_i += dim_[j]; }
        float idn = 1.0f / (tr_r*tr_r + tr_i*tr_i);
        float ur = wre[tid], ui = wim[tid];
        wre[tid] = (ur*tr_r + ui*tr_i) * idn;     // w = u * conj(tr) / |tr|^2
        wim[tid] = (ui*tr_r - ur*tr_i) * idn;
    }
    __syncthreads();

    // ---- Phase B: out[b,f,t] = sum_c conj(w_c) * x_c(t) ----
    float wr[8], wi[8];
    #pragma unroll
    for (int c = 0; c < 8; ++c) { wr[c] = wre[c]; wi[c] = wim[c]; }

    float2* outr = (float2*)out + (b*Ff + f)*P2;
    float2* outi = (float2*)out + (Bb*Ff)*P2 + (b*Ff + f)*P2;
    for (int p = tid; p < P2; p += 64) {
        float rx = 0.f, ry = 0.f, ix = 0.f, iy = 0.f;
        #pragma unroll
        for (int c = 0; c < 8; ++c) {
            float2 a  = xr2[p + c*cstride];
            float2 bb = xi2[p + c*cstride];
            rx += wr[c]*a.x + wi[c]*bb.x;
            ry += wr[c]*a.y + wi[c]*bb.y;
            ix += wr[c]*bb.x - wi[c]*a.x;
            iy += wr[c]*bb.y - wi[c]*a.y;
        }
        outr[p] = make_float2(rx, ry);
        outi[p] = make_float2(ix, iy);
    }
}

extern "C" void kernel_launch(void* const* d_in, const int* in_sizes, int n_in,
                              void* d_out, int out_size, void* d_ws, size_t ws_size,
                              hipStream_t stream) {
    const float* smask = (const float*)d_in[0];
    const float* nmask = (const float*)d_in[1];
    const float* cmr   = (const float*)d_in[2];
    const float* cmi   = (const float*)d_in[3];
    float* ws = (float*)d_ws;
    float* pmax_s = ws;                 // 8*8*1500 = 96000 floats
    float* pmax_n = ws + 96000;         // 96000
    float* inv_s  = ws + 192000;        // 12000
    float* inv_n  = ws + 204000;        // 12000  (total 864 KB)

    mask_pmax<<<dim3(6, 8, 8), 256, 0, stream>>>(smask, nmask, pmax_s, pmax_n);
    mask_inv <<<dim3(6, 8),    256, 0, stream>>>(pmax_s, pmax_n, inv_s, inv_n);
    mvdr_main<<<BF, 64, 0, stream>>>(smask, nmask, cmr, cmi, inv_s, inv_n, (float*)d_out);
}